// Round 12
// baseline (300.091 us; speedup 1.0000x reference)
//
#include <hip/hip_runtime.h>

#define BB 64
#define NN 128
#define INF_ 5
#define LATD 3
#define HIDD 64

__device__ __forceinline__ float bflo(unsigned u) { return __uint_as_float(u << 16); }
__device__ __forceinline__ float bfhi(unsigned u) { return __uint_as_float(u & 0xffff0000u); }
__device__ __forceinline__ unsigned bfpack(float a, float b) {
    unsigned ua = __float_as_uint(a), ub = __float_as_uint(b);
    unsigned ra = (ua + 0x7fffu + ((ua >> 16) & 1u)) >> 16;   // RNE
    unsigned rb = (ub + 0x7fffu + ((ub >> 16) & 1u)) >> 16;
    return ra | (rb << 16);
}

// ---------------------------------------------------------------------------
// Encoder (f64, expressions unchanged since r5 -> adjacency bits stable).
// Also zeroes o5/o6. Grid (B,4).
// ---------------------------------------------------------------------------
__global__ __launch_bounds__(256) void enc_kernel(
    const float* __restrict__ batch,
    const float* __restrict__ w1, const float* __restrict__ b1,
    const float* __restrict__ w2, const float* __restrict__ b2,
    const float* __restrict__ w3, const float* __restrict__ b3,
    double* __restrict__ aos,
    float* __restrict__ o0, float* __restrict__ o1, float* __restrict__ o4,
    float* __restrict__ o5)
{
    const int b = blockIdx.x;
    const int n0 = blockIdx.y * 32;
    const int tid = threadIdx.x;
    const int w = tid >> 6, lane = tid & 63;

    {   // zero adj + edge_dist (contiguous 8 MB starting at o5)
        const int blk = blockIdx.x * 4 + blockIdx.y;      // 0..255
        float4* z = (float4*)o5 + (size_t)blk * 2048;
        float4 zero = make_float4(0.f, 0.f, 0.f, 0.f);
        for (int q = tid; q < 2048; q += 256) z[q] = zero;
    }

    __shared__ double xs[32][6];
    __shared__ double w1s[INF_][HIDD];
    __shared__ float  w2s[HIDD * HIDD];
    __shared__ double w3s[HIDD][LATD];
    __shared__ double b1s[HIDD], b2s[HIDD], b3s[LATD];

    for (int idx = tid; idx < 32 * INF_; idx += 256) {
        int n = idx / INF_, c = idx % INF_;
        float v = batch[((size_t)b * NN + n0 + n) * INF_ + c];
        xs[n][c] = (double)v;
        if (c < 4) o0[((size_t)b * NN + n0 + n) * 4 + c] = v;
        else       o1[(size_t)b * NN + n0 + n] = v;
    }
    for (int idx = tid; idx < INF_ * HIDD; idx += 256)
        w1s[idx / HIDD][idx % HIDD] = (double)w1[idx];
    for (int idx = tid; idx < HIDD * HIDD; idx += 256)
        w2s[idx] = w2[idx];
    for (int idx = tid; idx < HIDD * LATD; idx += 256)
        w3s[idx / LATD][idx % LATD] = (double)w3[idx];
    if (tid < HIDD) {
        b1s[tid] = (double)b1[tid];
        b2s[tid] = (double)b2[tid];
    }
    if (tid < LATD) b3s[tid] = (double)b3[tid];
    __syncthreads();

    for (int r = 0; r < 8; ++r) {
        const int nl = w * 8 + r;
        const int n = n0 + nl;
        double h1v = b1s[lane];
        for (int k = 0; k < INF_; ++k) h1v += xs[nl][k] * w1s[k][lane];
        h1v = fmax(h1v, 0.0);
        double h2v = b2s[lane];
        for (int k = 0; k < HIDD; ++k) {
            double h1k = __shfl(h1v, k, 64);
            h2v += h1k * (double)w2s[k * HIDD + lane];
        }
        h2v = fmax(h2v, 0.0);
        double l0 = h2v * w3s[lane][0];
        double l1 = h2v * w3s[lane][1];
        double l2 = h2v * w3s[lane][2];
        for (int o = 32; o >= 1; o >>= 1) {
            l0 += __shfl_xor(l0, o, 64);
            l1 += __shfl_xor(l1, o, 64);
            l2 += __shfl_xor(l2, o, 64);
        }
        l0 += b3s[0]; l1 += b3s[1]; l2 += b3s[2];
        if (lane == 0) {
            double* A = aos + ((size_t)b * NN + n) * 4;
            A[0] = l0; A[1] = l1; A[2] = l2;
            A[3] = l0 * l0 + l1 * l1 + l2 * l2;
        }
        if (lane < LATD) {
            double lv = (lane == 0) ? l0 : ((lane == 1) ? l1 : l2);
            o4[((size_t)b * NN + n) * LATD + lane] = (float)lv;
        }
    }
}

// ---------------------------------------------------------------------------
// Gabriel (unchanged from r10): wave = pair stream with j-parity split,
// lane = witness k in registers, identity d2-r2 == (pk-pi).(pk-pj).
// ---------------------------------------------------------------------------
__global__ __launch_bounds__(256) void gabriel_kernel(
    const double* __restrict__ aos,
    float* __restrict__ o5, float* __restrict__ o6)
{
    const int b = blockIdx.y;
    const int w = threadIdx.x >> 6, lane = threadIdx.x & 63;
    const int u = blockIdx.x * 4 + w;          // 0..127
    const int v = u >> 1, par = u & 1;

    __shared__ double4 Ps[NN];
    const double2* src = (const double2*)(aos + (size_t)b * NN * 4);
    double2* dst = (double2*)Ps;
    for (int idx = threadIdx.x; idx < NN * 2; idx += 256) dst[idx] = src[idx];
    __syncthreads();

    const double4 A  = Ps[lane];
    const double4 Bq = Ps[lane + 64];

    for (int half = 0; half < 2; ++half) {
        const int i = (half == 0) ? v : 126 - v;
        if (half == 1 && i == v) break;
        const int jstart = (half == 0) ? (v + 1) : (127 - v);
        const int j0 = jstart + ((jstart ^ par) & 1);
        const double4 pi = Ps[i];
        const double aix = A.x - pi.x,  aiy = A.y - pi.y,  aiz = A.z - pi.z;
        const double bix = Bq.x - pi.x, biy = Bq.y - pi.y, biz = Bq.z - pi.z;
        const bool mA = (lane != i), mB = (lane + 64 != i);
        for (int j = j0; j < NN; j += 2) {
            double4 pj = Ps[j];
            double ajx = A.x - pj.x,  ajy = A.y - pj.y,  ajz = A.z - pj.z;
            double bjx = Bq.x - pj.x, bjy = Bq.y - pj.y, bjz = Bq.z - pj.z;
            double dA = aix * ajx + aiy * ajy + aiz * ajz;
            double dB = bix * bjx + biy * bjy + biz * bjz;
            bool tA = (dA < 0.0) && mA && (lane != j);
            bool tB = (dB < 0.0) && mB && (lane + 64 != j);
            if (!__any(tA || tB)) {
                if (lane == 0) {
                    double dx = pi.x - pj.x, dy = pi.y - pj.y, dz = pi.z - pj.z;
                    float d = (float)sqrt(dx * dx + dy * dy + dz * dz);
                    size_t ij = ((size_t)b * NN + i) * NN + j;
                    size_t ji = ((size_t)b * NN + j) * NN + i;
                    o5[ij] = 1.0f; o5[ji] = 1.0f;
                    o6[ij] = d;    o6[ji] = d;
                }
            }
        }
    }
}

// ---------------------------------------------------------------------------
// Attention v5. Structure as r11 (8 rows/block, 1024 blocks, 40 KB LDS,
// 4 blocks/CU), but the fused-linear epilogue is BARRIER-FREE:
// r11's matvec used __shfl chains (= ds_bpermute on CDNA: LDS-port +
// ~LDS latency) + 2 barriers + 16 KB weight staging per matvec — 9
// barriers/kernel, 61 us, VALUBusy 25%. v5: the wave's 2 output rows are
// written ONCE into the wave-private as2 row (no barrier), each matvec
// reads x as b64 broadcasts and streams W straight from global (coalesced,
// L2-resident) — no staging, no bpermute, 1 barrier per kernel.
// ---------------------------------------------------------------------------
struct AttnS {
    float  hls[NN * 66];     // 33792 B
    float2 as2[4][NN];       //  4096 B (wave-private rows; reused as x buf)
    float2 hr2[8][32];       //  2048 B
    float2 att2[32];         //   256 B
};

__device__ __forceinline__ void attn_stage_packed(
    AttnS& s, int tid, int b, int i0,
    const unsigned* __restrict__ hlp, const unsigned* __restrict__ hrp,
    const float* __restrict__ att)
{
    const unsigned* src = hlp + (size_t)b * NN * 32;
    for (int idx = tid; idx < NN * 32; idx += 256) {
        int j = idx >> 5, c = idx & 31;
        unsigned u = src[idx];
        *(float2*)&s.hls[j * 66 + 2 * c] = make_float2(bflo(u), bfhi(u));
    }
    unsigned u = hrp[((size_t)b * NN + i0) * 32 + tid];   // 8 rows * 32 words
    ((float2*)s.hr2)[tid] = make_float2(bflo(u), bfhi(u));
    if (tid < 32) s.att2[tid] = make_float2(att[2 * tid], att[2 * tid + 1]);
}

// Phase A (scores+softmax) + Phase B (aggregation). Caller barriers staging.
__device__ __forceinline__ void attn_phase(
    AttnS& s, int b, int i0, int w, int lane,
    const float* __restrict__ adjf, float& agg0, float& agg1)
{
    const int il0 = w * 2, il1 = il0 + 1;
    const int i_0 = i0 + il0, i_1 = i0 + il1;
    float s00 = 0.f, s01 = 0.f, s10 = 0.f, s11 = 0.f;
    {
        const float* hl0 = &s.hls[lane * 66];
        const float* hl1 = &s.hls[(lane + 64) * 66];
        #pragma unroll
        for (int c = 0; c < 32; ++c) {
            float2 av = s.att2[c];
            float2 r0 = s.hr2[il0][c];
            float2 r1 = s.hr2[il1][c];
            float2 g0 = *(const float2*)&hl0[2 * c];
            float2 g1 = *(const float2*)&hl1[2 * c];
            float e;
            e = r0.x + g0.x; e = fmaxf(e, 0.2f * e); s00 = fmaf(av.x, e, s00);
            e = r0.y + g0.y; e = fmaxf(e, 0.2f * e); s00 = fmaf(av.y, e, s00);
            e = r0.x + g1.x; e = fmaxf(e, 0.2f * e); s01 = fmaf(av.x, e, s01);
            e = r0.y + g1.y; e = fmaxf(e, 0.2f * e); s01 = fmaf(av.y, e, s01);
            e = r1.x + g0.x; e = fmaxf(e, 0.2f * e); s10 = fmaf(av.x, e, s10);
            e = r1.y + g0.y; e = fmaxf(e, 0.2f * e); s10 = fmaf(av.y, e, s10);
            e = r1.x + g1.x; e = fmaxf(e, 0.2f * e); s11 = fmaf(av.x, e, s11);
            e = r1.y + g1.y; e = fmaxf(e, 0.2f * e); s11 = fmaf(av.y, e, s11);
        }
    }
    {
        const float* ar0 = adjf + ((size_t)b * NN + i_0) * NN;
        const float* ar1 = adjf + ((size_t)b * NN + i_1) * NN;
        if (!((ar0[lane] != 0.f)      || (lane == i_0)))      s00 = -1e30f;
        if (!((ar0[lane + 64] != 0.f) || (lane + 64 == i_0))) s01 = -1e30f;
        if (!((ar1[lane] != 0.f)      || (lane == i_1)))      s10 = -1e30f;
        if (!((ar1[lane + 64] != 0.f) || (lane + 64 == i_1))) s11 = -1e30f;
    }
    float m0 = fmaxf(s00, s01), m1 = fmaxf(s10, s11);
    for (int o = 32; o >= 1; o >>= 1) {
        m0 = fmaxf(m0, __shfl_xor(m0, o, 64));
        m1 = fmaxf(m1, __shfl_xor(m1, o, 64));
    }
    float e00 = __expf(s00 - m0), e01 = __expf(s01 - m0);
    float e10 = __expf(s10 - m1), e11 = __expf(s11 - m1);
    float z0 = e00 + e01, z1 = e10 + e11;
    for (int o = 32; o >= 1; o >>= 1) {
        z0 += __shfl_xor(z0, o, 64);
        z1 += __shfl_xor(z1, o, 64);
    }
    float iv0 = 1.f / z0, iv1 = 1.f / z1;
    s.as2[w][lane]      = make_float2(e00 * iv0, e10 * iv1);
    s.as2[w][lane + 64] = make_float2(e01 * iv0, e11 * iv1);
    float o0a = 0.f, o1a = 0.f;
    for (int j = 0; j < NN; ++j) {
        float2 av = s.as2[w][j];
        float hv = s.hls[j * 66 + lane];
        o0a = fmaf(av.x, hv, o0a);
        o1a = fmaf(av.y, hv, o1a);
    }
    agg0 = o0a; agg1 = o1a;
}

// One fused-linear matvec: x (in wave-private as2 row, float2 per h) @ wmat.
// W streamed from global (coalesced per lane, L2-resident). No barriers.
__device__ __forceinline__ void mv_one(
    AttnS& s, int w, int lane, int b, int i0,
    const float* __restrict__ wmat, const float* __restrict__ bvec,
    unsigned* __restrict__ outp)
{
    float acc0 = bvec[lane], acc1 = acc0;
    #pragma unroll
    for (int h = 0; h < HIDD; ++h) {
        float2 xv = s.as2[w][h];              // b64 broadcast (wave-private)
        float wv = wmat[h * HIDD + lane];     // global coalesced, L2
        acc0 = fmaf(xv.x, wv, acc0);
        acc1 = fmaf(xv.y, wv, acc1);
    }
    float p0 = __shfl_xor(acc0, 1, 64);
    float p1 = __shfl_xor(acc1, 1, 64);
    if ((lane & 1) == 0) {
        outp[((size_t)b * NN + i0 + w * 2 + 0) * 32 + (lane >> 1)] = bfpack(acc0, p0);
        outp[((size_t)b * NN + i0 + w * 2 + 1) * 32 + (lane >> 1)] = bfpack(acc1, p1);
    }
}

// ---- layer 1: lin1 folded into staging (Cin=1), lin2 folded into epilogue --
__global__ __launch_bounds__(256, 4) void attnA_kernel(
    const float* __restrict__ latf,
    const float* __restrict__ wl1, const float* __restrict__ bl1,
    const float* __restrict__ wr1, const float* __restrict__ br1,
    const float* __restrict__ att, const float* __restrict__ bias,
    const float* __restrict__ adjf,
    const float* __restrict__ wl2, const float* __restrict__ bl2,
    const float* __restrict__ wr2, const float* __restrict__ br2,
    unsigned* __restrict__ hl2p, unsigned* __restrict__ hr2p)
{
    __shared__ AttnS s;
    const int bx = blockIdx.x;
    const int b = bx >> 4, i0 = (bx & 15) << 3;
    const int tid = threadIdx.x, w = tid >> 6, lane = tid & 63;

    {   // hl1[j][h] = x0[j]*wl1[h] + bl1[h];  x0 = latent[...,2] (wave-uniform)
        float wv = wl1[lane], bv = bl1[lane];
        for (int m = 0; m < 32; ++m) {
            int j = w + 4 * m;
            float x0 = latf[((size_t)b * NN + j) * LATD + 2];
            s.hls[j * 66 + lane] = fmaf(x0, wv, bv);
        }
    }
    {   // hr1 for this block's 8 rows
        int il = tid >> 5, c = tid & 31;
        float x0 = latf[((size_t)b * NN + i0 + il) * LATD + 2];
        s.hr2[il][c] = make_float2(fmaf(x0, wr1[2 * c], br1[2 * c]),
                                   fmaf(x0, wr1[2 * c + 1], br1[2 * c + 1]));
    }
    if (tid < 32) s.att2[tid] = make_float2(att[2 * tid], att[2 * tid + 1]);
    float bsv = bias[lane];
    __syncthreads();

    float agg0, agg1;
    attn_phase(s, b, i0, w, lane, adjf, agg0, agg1);
    float out0 = fmaxf(agg0 + bsv, 0.f);
    float out1 = fmaxf(agg1 + bsv, 0.f);

    s.as2[w][lane] = make_float2(out0, out1);     // wave-private x buffer
    mv_one(s, w, lane, b, i0, wl2, bl2, hl2p);
    mv_one(s, w, lane, b, i0, wr2, br2, hr2p);
}

// ---- layer 2: lin3 + lin4 folded into epilogue ----------------------------
__global__ __launch_bounds__(256, 4) void attnB_kernel(
    const unsigned* __restrict__ hlp, const unsigned* __restrict__ hrp,
    const float* __restrict__ att, const float* __restrict__ bias,
    const float* __restrict__ adjf,
    const float* __restrict__ wl3, const float* __restrict__ bl3,
    const float* __restrict__ wr3, const float* __restrict__ br3,
    const float* __restrict__ wl4, const float* __restrict__ bl4,
    const float* __restrict__ wr4, const float* __restrict__ br4,
    unsigned* __restrict__ hl3p, unsigned* __restrict__ hr3p,
    unsigned* __restrict__ hl4p, unsigned* __restrict__ hr4p)
{
    __shared__ AttnS s;
    const int bx = blockIdx.x;
    const int b = bx >> 4, i0 = (bx & 15) << 3;
    const int tid = threadIdx.x, w = tid >> 6, lane = tid & 63;

    attn_stage_packed(s, tid, b, i0, hlp, hrp, att);
    float bsv = bias[lane];
    __syncthreads();

    float agg0, agg1;
    attn_phase(s, b, i0, w, lane, adjf, agg0, agg1);
    float out0 = fmaxf(agg0 + bsv, 0.f);
    float out1 = fmaxf(agg1 + bsv, 0.f);

    s.as2[w][lane] = make_float2(out0, out1);     // wave-private x buffer
    mv_one(s, w, lane, b, i0, wl3, bl3, hl3p);
    mv_one(s, w, lane, b, i0, wr3, br3, hr3p);
    mv_one(s, w, lane, b, i0, wl4, bl4, hl4p);
    mv_one(s, w, lane, b, i0, wr4, br4, hr4p);
}

// ---- layers 3 & 4: skip + output heads ------------------------------------
template <int C>
__device__ __forceinline__ void attn_head(
    AttnS& s, int tid, int b, int i0,
    const unsigned* __restrict__ hlp, const unsigned* __restrict__ hrp,
    const float* __restrict__ att, const float* __restrict__ bias,
    const float* __restrict__ adjf, const float* __restrict__ latf,
    const float* __restrict__ skw, const float* __restrict__ skb,
    const float* __restrict__ head_w, const float* __restrict__ head_b,
    float* __restrict__ head_out)
{
    const int w = tid >> 6, lane = tid & 63;
    attn_stage_packed(s, tid, b, i0, hlp, hrp, att);
    float bsv = bias[lane];
    float sw0 = skw[lane], sw1 = skw[64 + lane], sw2 = skw[128 + lane];
    float sbv = skb[lane];
    __syncthreads();

    float agg0, agg1;
    attn_phase(s, b, i0, w, lane, adjf, agg0, agg1);

    #pragma unroll
    for (int r = 0; r < 2; ++r) {
        const int i = i0 + w * 2 + r;
        float out = ((r == 0) ? agg0 : agg1) + bsv;
        const float* lr = latf + ((size_t)b * NN + i) * LATD;
        float sk = sbv;
        sk = fmaf(lr[0], sw0, sk);
        sk = fmaf(lr[1], sw1, sk);
        sk = fmaf(lr[2], sw2, sk);
        out = fmaxf(out + 0.1f * sk, 0.f);
        float hv[C];
        #pragma unroll
        for (int c = 0; c < C; ++c) {
            float vv = out * head_w[lane * C + c];
            for (int o = 32; o >= 1; o >>= 1) vv += __shfl_xor(vv, o, 64);
            hv[c] = vv + head_b[c];
        }
        if (lane == 0)
            for (int c = 0; c < C; ++c)
                head_out[((size_t)b * NN + i) * C + c] = hv[c];
    }
}

__global__ __launch_bounds__(256, 4) void attnCD_kernel(
    const unsigned* __restrict__ hl3p, const unsigned* __restrict__ hr3p,
    const unsigned* __restrict__ hl4p, const unsigned* __restrict__ hr4p,
    const float* __restrict__ att3, const float* __restrict__ b3,
    const float* __restrict__ att4, const float* __restrict__ b4,
    const float* __restrict__ adjf, const float* __restrict__ latf,
    const float* __restrict__ skw, const float* __restrict__ skb,
    const float* __restrict__ lab_w, const float* __restrict__ lab_b, float* __restrict__ o2,
    const float* __restrict__ val_w, const float* __restrict__ val_b, float* __restrict__ o3)
{
    __shared__ AttnS s;
    const int b = blockIdx.x >> 4, i0 = (blockIdx.x & 15) << 3;
    if (blockIdx.y == 0)
        attn_head<4>(s, threadIdx.x, b, i0, hl3p, hr3p, att3, b3, adjf, latf,
                     skw, skb, lab_w, lab_b, o2);
    else
        attn_head<1>(s, threadIdx.x, b, i0, hl4p, hr4p, att4, b4, adjf, latf,
                     skw, skb, val_w, val_b, o3);
}

// ---------------------------------------------------------------------------
extern "C" void kernel_launch(void* const* d_in, const int* in_sizes, int n_in,
                              void* d_out, int out_size, void* d_ws, size_t ws_size,
                              hipStream_t stream)
{
    const float* batch  = (const float*)d_in[0];
    const float* enc_w1 = (const float*)d_in[1];
    const float* enc_b1 = (const float*)d_in[2];
    const float* enc_w2 = (const float*)d_in[3];
    const float* enc_b2 = (const float*)d_in[4];
    const float* enc_w3 = (const float*)d_in[5];
    const float* enc_b3 = (const float*)d_in[6];
    const float* g_wl[4]  = {(const float*)d_in[7],  (const float*)d_in[13], (const float*)d_in[19], (const float*)d_in[25]};
    const float* g_bl[4]  = {(const float*)d_in[8],  (const float*)d_in[14], (const float*)d_in[20], (const float*)d_in[26]};
    const float* g_wr[4]  = {(const float*)d_in[9],  (const float*)d_in[15], (const float*)d_in[21], (const float*)d_in[27]};
    const float* g_br[4]  = {(const float*)d_in[10], (const float*)d_in[16], (const float*)d_in[22], (const float*)d_in[28]};
    const float* g_att[4] = {(const float*)d_in[11], (const float*)d_in[17], (const float*)d_in[23], (const float*)d_in[29]};
    const float* g_b[4]   = {(const float*)d_in[12], (const float*)d_in[18], (const float*)d_in[24], (const float*)d_in[30]};
    const float* lab_w = (const float*)d_in[31];
    const float* lab_b = (const float*)d_in[32];
    const float* val_w = (const float*)d_in[33];
    const float* val_b = (const float*)d_in[34];
    const float* skw   = (const float*)d_in[35];
    const float* skb   = (const float*)d_in[36];

    float* out = (float*)d_out;
    float* o0 = out;            // batch[:,:,:4]   32768
    float* o1 = out + 32768;    // batch[:,:,4:5]   8192
    float* o2 = out + 40960;    // logits          32768
    float* o3 = out + 73728;    // values           8192
    float* o4 = out + 81920;    // latent          24576  (doubles as latf)
    float* o5 = out + 106496;   // adj           1048576
    float* o6 = out + 1155072;  // edge_dist     1048576

    // Scratch: 6.25 MB.
    char* p = (char*)d_ws;
    auto carve = [&](size_t bytes) { void* r = (void*)p; p += (bytes + 255) & ~(size_t)255; return r; };
    double*   aos  = (double*)  carve((size_t)BB * NN * 4 * 8);   // 256 KB
    unsigned* hl2p = (unsigned*)carve((size_t)BB * NN * 32 * 4);  // 1 MB
    unsigned* hr2p = (unsigned*)carve((size_t)BB * NN * 32 * 4);
    unsigned* hl3p = (unsigned*)carve((size_t)BB * NN * 32 * 4);
    unsigned* hr3p = (unsigned*)carve((size_t)BB * NN * 32 * 4);
    unsigned* hl4p = (unsigned*)carve((size_t)BB * NN * 32 * 4);
    unsigned* hr4p = (unsigned*)carve((size_t)BB * NN * 32 * 4);

    enc_kernel<<<dim3(BB, 4), 256, 0, stream>>>(batch, enc_w1, enc_b1, enc_w2, enc_b2,
                                                enc_w3, enc_b3, aos, o0, o1, o4, o5);
    gabriel_kernel<<<dim3(32, BB), 256, 0, stream>>>(aos, o5, o6);

    // layer 1 (lin1 + lin2 fused) -> hl2p/hr2p
    attnA_kernel<<<BB * 16, 256, 0, stream>>>(o4,
        g_wl[0], g_bl[0], g_wr[0], g_br[0], g_att[0], g_b[0], o5,
        g_wl[1], g_bl[1], g_wr[1], g_br[1], hl2p, hr2p);
    // layer 2 (lin3 + lin4 fused) -> hl3p/hr3p/hl4p/hr4p
    attnB_kernel<<<BB * 16, 256, 0, stream>>>(hl2p, hr2p,
        g_att[1], g_b[1], o5,
        g_wl[2], g_bl[2], g_wr[2], g_br[2],
        g_wl[3], g_bl[3], g_wr[3], g_br[3],
        hl3p, hr3p, hl4p, hr4p);
    // layers 3 + 4 with skip + heads -> o2/o3
    attnCD_kernel<<<dim3(BB * 16, 2), 256, 0, stream>>>(hl3p, hr3p, hl4p, hr4p,
        g_att[2], g_b[2], g_att[3], g_b[3], o5, o4, skw, skb,
        lab_w, lab_b, o2, val_w, val_b, o3);
}

// Round 13
// 267.072 us; speedup vs baseline: 1.1236x; 1.1236x over previous
//
#include <hip/hip_runtime.h>

#define BB 64
#define NN 128
#define INF_ 5
#define LATD 3
#define HIDD 64

__device__ __forceinline__ float bflo(unsigned u) { return __uint_as_float(u << 16); }
__device__ __forceinline__ float bfhi(unsigned u) { return __uint_as_float(u & 0xffff0000u); }
__device__ __forceinline__ unsigned bfpack(float a, float b) {
    unsigned ua = __float_as_uint(a), ub = __float_as_uint(b);
    unsigned ra = (ua + 0x7fffu + ((ua >> 16) & 1u)) >> 16;   // RNE
    unsigned rb = (ub + 0x7fffu + ((ub >> 16) & 1u)) >> 16;
    return ra | (rb << 16);
}

// ---------------------------------------------------------------------------
// Encoder (f64, expressions unchanged since r5 -> adjacency bits stable).
// Also zeroes o5/o6. Grid (B,4).
// ---------------------------------------------------------------------------
__global__ __launch_bounds__(256) void enc_kernel(
    const float* __restrict__ batch,
    const float* __restrict__ w1, const float* __restrict__ b1,
    const float* __restrict__ w2, const float* __restrict__ b2,
    const float* __restrict__ w3, const float* __restrict__ b3,
    double* __restrict__ aos,
    float* __restrict__ o0, float* __restrict__ o1, float* __restrict__ o4,
    float* __restrict__ o5)
{
    const int b = blockIdx.x;
    const int n0 = blockIdx.y * 32;
    const int tid = threadIdx.x;
    const int w = tid >> 6, lane = tid & 63;

    {   // zero adj + edge_dist (contiguous 8 MB starting at o5)
        const int blk = blockIdx.x * 4 + blockIdx.y;      // 0..255
        float4* z = (float4*)o5 + (size_t)blk * 2048;
        float4 zero = make_float4(0.f, 0.f, 0.f, 0.f);
        for (int q = tid; q < 2048; q += 256) z[q] = zero;
    }

    __shared__ double xs[32][6];
    __shared__ double w1s[INF_][HIDD];
    __shared__ float  w2s[HIDD * HIDD];
    __shared__ double w3s[HIDD][LATD];
    __shared__ double b1s[HIDD], b2s[HIDD], b3s[LATD];

    for (int idx = tid; idx < 32 * INF_; idx += 256) {
        int n = idx / INF_, c = idx % INF_;
        float v = batch[((size_t)b * NN + n0 + n) * INF_ + c];
        xs[n][c] = (double)v;
        if (c < 4) o0[((size_t)b * NN + n0 + n) * 4 + c] = v;
        else       o1[(size_t)b * NN + n0 + n] = v;
    }
    for (int idx = tid; idx < INF_ * HIDD; idx += 256)
        w1s[idx / HIDD][idx % HIDD] = (double)w1[idx];
    for (int idx = tid; idx < HIDD * HIDD; idx += 256)
        w2s[idx] = w2[idx];
    for (int idx = tid; idx < HIDD * LATD; idx += 256)
        w3s[idx / LATD][idx % LATD] = (double)w3[idx];
    if (tid < HIDD) {
        b1s[tid] = (double)b1[tid];
        b2s[tid] = (double)b2[tid];
    }
    if (tid < LATD) b3s[tid] = (double)b3[tid];
    __syncthreads();

    for (int r = 0; r < 8; ++r) {
        const int nl = w * 8 + r;
        const int n = n0 + nl;
        double h1v = b1s[lane];
        for (int k = 0; k < INF_; ++k) h1v += xs[nl][k] * w1s[k][lane];
        h1v = fmax(h1v, 0.0);
        double h2v = b2s[lane];
        for (int k = 0; k < HIDD; ++k) {
            double h1k = __shfl(h1v, k, 64);
            h2v += h1k * (double)w2s[k * HIDD + lane];
        }
        h2v = fmax(h2v, 0.0);
        double l0 = h2v * w3s[lane][0];
        double l1 = h2v * w3s[lane][1];
        double l2 = h2v * w3s[lane][2];
        for (int o = 32; o >= 1; o >>= 1) {
            l0 += __shfl_xor(l0, o, 64);
            l1 += __shfl_xor(l1, o, 64);
            l2 += __shfl_xor(l2, o, 64);
        }
        l0 += b3s[0]; l1 += b3s[1]; l2 += b3s[2];
        if (lane == 0) {
            double* A = aos + ((size_t)b * NN + n) * 4;
            A[0] = l0; A[1] = l1; A[2] = l2;
            A[3] = l0 * l0 + l1 * l1 + l2 * l2;
        }
        if (lane < LATD) {
            double lv = (lane == 0) ? l0 : ((lane == 1) ? l1 : l2);
            o4[((size_t)b * NN + n) * LATD + lane] = (float)lv;
        }
    }
}

// ---------------------------------------------------------------------------
// Gabriel (unchanged from r10): wave = pair stream with j-parity split,
// lane = witness k in registers, identity d2-r2 == (pk-pi).(pk-pj).
// ---------------------------------------------------------------------------
__global__ __launch_bounds__(256) void gabriel_kernel(
    const double* __restrict__ aos,
    float* __restrict__ o5, float* __restrict__ o6)
{
    const int b = blockIdx.y;
    const int w = threadIdx.x >> 6, lane = threadIdx.x & 63;
    const int u = blockIdx.x * 4 + w;          // 0..127
    const int v = u >> 1, par = u & 1;

    __shared__ double4 Ps[NN];
    const double2* src = (const double2*)(aos + (size_t)b * NN * 4);
    double2* dst = (double2*)Ps;
    for (int idx = threadIdx.x; idx < NN * 2; idx += 256) dst[idx] = src[idx];
    __syncthreads();

    const double4 A  = Ps[lane];
    const double4 Bq = Ps[lane + 64];

    for (int half = 0; half < 2; ++half) {
        const int i = (half == 0) ? v : 126 - v;
        if (half == 1 && i == v) break;
        const int jstart = (half == 0) ? (v + 1) : (127 - v);
        const int j0 = jstart + ((jstart ^ par) & 1);
        const double4 pi = Ps[i];
        const double aix = A.x - pi.x,  aiy = A.y - pi.y,  aiz = A.z - pi.z;
        const double bix = Bq.x - pi.x, biy = Bq.y - pi.y, biz = Bq.z - pi.z;
        const bool mA = (lane != i), mB = (lane + 64 != i);
        for (int j = j0; j < NN; j += 2) {
            double4 pj = Ps[j];
            double ajx = A.x - pj.x,  ajy = A.y - pj.y,  ajz = A.z - pj.z;
            double bjx = Bq.x - pj.x, bjy = Bq.y - pj.y, bjz = Bq.z - pj.z;
            double dA = aix * ajx + aiy * ajy + aiz * ajz;
            double dB = bix * bjx + biy * bjy + biz * bjz;
            bool tA = (dA < 0.0) && mA && (lane != j);
            bool tB = (dB < 0.0) && mB && (lane + 64 != j);
            if (!__any(tA || tB)) {
                if (lane == 0) {
                    double dx = pi.x - pj.x, dy = pi.y - pj.y, dz = pi.z - pj.z;
                    float d = (float)sqrt(dx * dx + dy * dy + dz * dz);
                    size_t ij = ((size_t)b * NN + i) * NN + j;
                    size_t ji = ((size_t)b * NN + j) * NN + i;
                    o5[ij] = 1.0f; o5[ji] = 1.0f;
                    o6[ij] = d;    o6[ji] = d;
                }
            }
        }
    }
}

// ---------------------------------------------------------------------------
// Attention v6. r10-12 showed three different epilogues all land ~300 total:
// attn is stall-dominated. v6 consolidates: matvec epilogue stages W into
// the post-Phase-B-dead hls region (32 KB rounds; attnB 5 barriers vs r11's
// 9) with x from the wave-private as2 row — no bpermute chains (r11) and no
// 64 KB/block global W streaming (r12). Adjacency loads hoisted above
// Phase A to overlap their ~500-cyc latency with the score loop.
// ---------------------------------------------------------------------------
struct AttnS {
    float  hls[NN * 66];     // 33792 B (reused as W buffer in epilogue)
    float2 as2[4][NN];       //  4096 B (wave-private; reused as x buffer)
    float2 hr2[8][32];       //  2048 B
    float2 att2[32];         //   256 B
};

__device__ __forceinline__ void attn_stage_packed(
    AttnS& s, int tid, int b, int i0,
    const unsigned* __restrict__ hlp, const unsigned* __restrict__ hrp,
    const float* __restrict__ att)
{
    const unsigned* src = hlp + (size_t)b * NN * 32;
    for (int idx = tid; idx < NN * 32; idx += 256) {
        int j = idx >> 5, c = idx & 31;
        unsigned u = src[idx];
        *(float2*)&s.hls[j * 66 + 2 * c] = make_float2(bflo(u), bfhi(u));
    }
    unsigned u = hrp[((size_t)b * NN + i0) * 32 + tid];   // 8 rows * 32 words
    ((float2*)s.hr2)[tid] = make_float2(bflo(u), bfhi(u));
    if (tid < 32) s.att2[tid] = make_float2(att[2 * tid], att[2 * tid + 1]);
}

// Phase A (scores+softmax) + Phase B (aggregation). Caller barriers staging.
__device__ __forceinline__ void attn_phase(
    AttnS& s, int b, int i0, int w, int lane,
    const float* __restrict__ adjf, float& agg0, float& agg1)
{
    const int il0 = w * 2, il1 = il0 + 1;
    const int i_0 = i0 + il0, i_1 = i0 + il1;

    // hoist adjacency loads (global, ~500 cyc) above the score loop
    const float* ar0 = adjf + ((size_t)b * NN + i_0) * NN;
    const float* ar1 = adjf + ((size_t)b * NN + i_1) * NN;
    float ad00 = ar0[lane], ad01 = ar0[lane + 64];
    float ad10 = ar1[lane], ad11 = ar1[lane + 64];

    float s00 = 0.f, s01 = 0.f, s10 = 0.f, s11 = 0.f;
    {
        const float* hl0 = &s.hls[lane * 66];
        const float* hl1 = &s.hls[(lane + 64) * 66];
        #pragma unroll
        for (int c = 0; c < 32; ++c) {
            float2 av = s.att2[c];
            float2 r0 = s.hr2[il0][c];
            float2 r1 = s.hr2[il1][c];
            float2 g0 = *(const float2*)&hl0[2 * c];
            float2 g1 = *(const float2*)&hl1[2 * c];
            float e;
            e = r0.x + g0.x; e = fmaxf(e, 0.2f * e); s00 = fmaf(av.x, e, s00);
            e = r0.y + g0.y; e = fmaxf(e, 0.2f * e); s00 = fmaf(av.y, e, s00);
            e = r0.x + g1.x; e = fmaxf(e, 0.2f * e); s01 = fmaf(av.x, e, s01);
            e = r0.y + g1.y; e = fmaxf(e, 0.2f * e); s01 = fmaf(av.y, e, s01);
            e = r1.x + g0.x; e = fmaxf(e, 0.2f * e); s10 = fmaf(av.x, e, s10);
            e = r1.y + g0.y; e = fmaxf(e, 0.2f * e); s10 = fmaf(av.y, e, s10);
            e = r1.x + g1.x; e = fmaxf(e, 0.2f * e); s11 = fmaf(av.x, e, s11);
            e = r1.y + g1.y; e = fmaxf(e, 0.2f * e); s11 = fmaf(av.y, e, s11);
        }
    }
    if (!((ad00 != 0.f) || (lane == i_0)))      s00 = -1e30f;
    if (!((ad01 != 0.f) || (lane + 64 == i_0))) s01 = -1e30f;
    if (!((ad10 != 0.f) || (lane == i_1)))      s10 = -1e30f;
    if (!((ad11 != 0.f) || (lane + 64 == i_1))) s11 = -1e30f;

    float m0 = fmaxf(s00, s01), m1 = fmaxf(s10, s11);
    for (int o = 32; o >= 1; o >>= 1) {
        m0 = fmaxf(m0, __shfl_xor(m0, o, 64));
        m1 = fmaxf(m1, __shfl_xor(m1, o, 64));
    }
    float e00 = __expf(s00 - m0), e01 = __expf(s01 - m0);
    float e10 = __expf(s10 - m1), e11 = __expf(s11 - m1);
    float z0 = e00 + e01, z1 = e10 + e11;
    for (int o = 32; o >= 1; o >>= 1) {
        z0 += __shfl_xor(z0, o, 64);
        z1 += __shfl_xor(z1, o, 64);
    }
    float iv0 = 1.f / z0, iv1 = 1.f / z1;
    s.as2[w][lane]      = make_float2(e00 * iv0, e10 * iv1);
    s.as2[w][lane + 64] = make_float2(e01 * iv0, e11 * iv1);
    float o0a = 0.f, o1a = 0.f;
    for (int j = 0; j < NN; ++j) {
        float2 av = s.as2[w][j];
        float hv = s.hls[j * 66 + lane];
        o0a = fmaf(av.x, hv, o0a);
        o1a = fmaf(av.y, hv, o1a);
    }
    agg0 = o0a; agg1 = o1a;
}

// Stage two 16 KB weight matrices into the dead hls region (32 KB).
__device__ __forceinline__ void stage_w2(
    AttnS& s, int tid, const float* __restrict__ wa, const float* __restrict__ wb)
{
    float4* d4 = (float4*)s.hls;
    const float4* a4 = (const float4*)wa;
    const float4* b4 = (const float4*)wb;
    for (int idx = tid; idx < 1024; idx += 256) d4[idx] = a4[idx];
    for (int idx = tid; idx < 1024; idx += 256) d4[1024 + idx] = b4[idx];
}

// Matvec: x in wave-private as2 row (b64 broadcasts), W from LDS
// (lane-indexed, bank = lane%32 -> 2-way alias, free). No barriers inside.
__device__ __forceinline__ void mv_lds(
    AttnS& s, const float* __restrict__ Wlds, int w, int lane, int b, int i0,
    const float* __restrict__ bvec, unsigned* __restrict__ outp)
{
    float acc0 = bvec[lane], acc1 = acc0;
    #pragma unroll
    for (int h = 0; h < HIDD; ++h) {
        float2 xv = s.as2[w][h];
        float wv = Wlds[h * HIDD + lane];
        acc0 = fmaf(xv.x, wv, acc0);
        acc1 = fmaf(xv.y, wv, acc1);
    }
    float p0 = __shfl_xor(acc0, 1, 64);
    float p1 = __shfl_xor(acc1, 1, 64);
    if ((lane & 1) == 0) {
        outp[((size_t)b * NN + i0 + w * 2 + 0) * 32 + (lane >> 1)] = bfpack(acc0, p0);
        outp[((size_t)b * NN + i0 + w * 2 + 1) * 32 + (lane >> 1)] = bfpack(acc1, p1);
    }
}

// ---- layer 1: lin1 folded into staging (Cin=1), lin2 folded into epilogue --
__global__ __launch_bounds__(256, 4) void attnA_kernel(
    const float* __restrict__ latf,
    const float* __restrict__ wl1, const float* __restrict__ bl1,
    const float* __restrict__ wr1, const float* __restrict__ br1,
    const float* __restrict__ att, const float* __restrict__ bias,
    const float* __restrict__ adjf,
    const float* __restrict__ wl2, const float* __restrict__ bl2,
    const float* __restrict__ wr2, const float* __restrict__ br2,
    unsigned* __restrict__ hl2p, unsigned* __restrict__ hr2p)
{
    __shared__ AttnS s;
    const int bx = blockIdx.x;
    const int b = bx >> 4, i0 = (bx & 15) << 3;
    const int tid = threadIdx.x, w = tid >> 6, lane = tid & 63;

    {   // hl1[j][h] = x0[j]*wl1[h] + bl1[h];  x0 = latent[...,2] (wave-uniform)
        float wv = wl1[lane], bv = bl1[lane];
        for (int m = 0; m < 32; ++m) {
            int j = w + 4 * m;
            float x0 = latf[((size_t)b * NN + j) * LATD + 2];
            s.hls[j * 66 + lane] = fmaf(x0, wv, bv);
        }
    }
    {   // hr1 for this block's 8 rows
        int il = tid >> 5, c = tid & 31;
        float x0 = latf[((size_t)b * NN + i0 + il) * LATD + 2];
        s.hr2[il][c] = make_float2(fmaf(x0, wr1[2 * c], br1[2 * c]),
                                   fmaf(x0, wr1[2 * c + 1], br1[2 * c + 1]));
    }
    if (tid < 32) s.att2[tid] = make_float2(att[2 * tid], att[2 * tid + 1]);
    float bsv = bias[lane];
    __syncthreads();

    float agg0, agg1;
    attn_phase(s, b, i0, w, lane, adjf, agg0, agg1);
    float out0 = fmaxf(agg0 + bsv, 0.f);
    float out1 = fmaxf(agg1 + bsv, 0.f);
    s.as2[w][lane] = make_float2(out0, out1);     // wave-private x buffer
    __syncthreads();                               // all waves done with hls
    stage_w2(s, tid, wl2, wr2);
    __syncthreads();
    mv_lds(s, s.hls,        w, lane, b, i0, bl2, hl2p);
    mv_lds(s, s.hls + 4096, w, lane, b, i0, br2, hr2p);
}

// ---- layer 2: lin3 + lin4 folded into epilogue (two 32 KB W rounds) -------
__global__ __launch_bounds__(256, 4) void attnB_kernel(
    const unsigned* __restrict__ hlp, const unsigned* __restrict__ hrp,
    const float* __restrict__ att, const float* __restrict__ bias,
    const float* __restrict__ adjf,
    const float* __restrict__ wl3, const float* __restrict__ bl3,
    const float* __restrict__ wr3, const float* __restrict__ br3,
    const float* __restrict__ wl4, const float* __restrict__ bl4,
    const float* __restrict__ wr4, const float* __restrict__ br4,
    unsigned* __restrict__ hl3p, unsigned* __restrict__ hr3p,
    unsigned* __restrict__ hl4p, unsigned* __restrict__ hr4p)
{
    __shared__ AttnS s;
    const int bx = blockIdx.x;
    const int b = bx >> 4, i0 = (bx & 15) << 3;
    const int tid = threadIdx.x, w = tid >> 6, lane = tid & 63;

    attn_stage_packed(s, tid, b, i0, hlp, hrp, att);
    float bsv = bias[lane];
    __syncthreads();

    float agg0, agg1;
    attn_phase(s, b, i0, w, lane, adjf, agg0, agg1);
    float out0 = fmaxf(agg0 + bsv, 0.f);
    float out1 = fmaxf(agg1 + bsv, 0.f);
    s.as2[w][lane] = make_float2(out0, out1);     // wave-private x buffer
    __syncthreads();                               // all waves done with hls
    stage_w2(s, tid, wl3, wr3);
    __syncthreads();
    mv_lds(s, s.hls,        w, lane, b, i0, bl3, hl3p);
    mv_lds(s, s.hls + 4096, w, lane, b, i0, br3, hr3p);
    __syncthreads();
    stage_w2(s, tid, wl4, wr4);
    __syncthreads();
    mv_lds(s, s.hls,        w, lane, b, i0, bl4, hl4p);
    mv_lds(s, s.hls + 4096, w, lane, b, i0, br4, hr4p);
}

// ---- layers 3 & 4: skip + output heads ------------------------------------
template <int C>
__device__ __forceinline__ void attn_head(
    AttnS& s, int tid, int b, int i0,
    const unsigned* __restrict__ hlp, const unsigned* __restrict__ hrp,
    const float* __restrict__ att, const float* __restrict__ bias,
    const float* __restrict__ adjf, const float* __restrict__ latf,
    const float* __restrict__ skw, const float* __restrict__ skb,
    const float* __restrict__ head_w, const float* __restrict__ head_b,
    float* __restrict__ head_out)
{
    const int w = tid >> 6, lane = tid & 63;
    attn_stage_packed(s, tid, b, i0, hlp, hrp, att);
    float bsv = bias[lane];
    float sw0 = skw[lane], sw1 = skw[64 + lane], sw2 = skw[128 + lane];
    float sbv = skb[lane];
    __syncthreads();

    float agg0, agg1;
    attn_phase(s, b, i0, w, lane, adjf, agg0, agg1);

    #pragma unroll
    for (int r = 0; r < 2; ++r) {
        const int i = i0 + w * 2 + r;
        float out = ((r == 0) ? agg0 : agg1) + bsv;
        const float* lr = latf + ((size_t)b * NN + i) * LATD;
        float sk = sbv;
        sk = fmaf(lr[0], sw0, sk);
        sk = fmaf(lr[1], sw1, sk);
        sk = fmaf(lr[2], sw2, sk);
        out = fmaxf(out + 0.1f * sk, 0.f);
        float hv[C];
        #pragma unroll
        for (int c = 0; c < C; ++c) {
            float vv = out * head_w[lane * C + c];
            for (int o = 32; o >= 1; o >>= 1) vv += __shfl_xor(vv, o, 64);
            hv[c] = vv + head_b[c];
        }
        if (lane == 0)
            for (int c = 0; c < C; ++c)
                head_out[((size_t)b * NN + i) * C + c] = hv[c];
    }
}

__global__ __launch_bounds__(256, 4) void attnCD_kernel(
    const unsigned* __restrict__ hl3p, const unsigned* __restrict__ hr3p,
    const unsigned* __restrict__ hl4p, const unsigned* __restrict__ hr4p,
    const float* __restrict__ att3, const float* __restrict__ b3,
    const float* __restrict__ att4, const float* __restrict__ b4,
    const float* __restrict__ adjf, const float* __restrict__ latf,
    const float* __restrict__ skw, const float* __restrict__ skb,
    const float* __restrict__ lab_w, const float* __restrict__ lab_b, float* __restrict__ o2,
    const float* __restrict__ val_w, const float* __restrict__ val_b, float* __restrict__ o3)
{
    __shared__ AttnS s;
    const int b = blockIdx.x >> 4, i0 = (blockIdx.x & 15) << 3;
    if (blockIdx.y == 0)
        attn_head<4>(s, threadIdx.x, b, i0, hl3p, hr3p, att3, b3, adjf, latf,
                     skw, skb, lab_w, lab_b, o2);
    else
        attn_head<1>(s, threadIdx.x, b, i0, hl4p, hr4p, att4, b4, adjf, latf,
                     skw, skb, val_w, val_b, o3);
}

// ---------------------------------------------------------------------------
extern "C" void kernel_launch(void* const* d_in, const int* in_sizes, int n_in,
                              void* d_out, int out_size, void* d_ws, size_t ws_size,
                              hipStream_t stream)
{
    const float* batch  = (const float*)d_in[0];
    const float* enc_w1 = (const float*)d_in[1];
    const float* enc_b1 = (const float*)d_in[2];
    const float* enc_w2 = (const float*)d_in[3];
    const float* enc_b2 = (const float*)d_in[4];
    const float* enc_w3 = (const float*)d_in[5];
    const float* enc_b3 = (const float*)d_in[6];
    const float* g_wl[4]  = {(const float*)d_in[7],  (const float*)d_in[13], (const float*)d_in[19], (const float*)d_in[25]};
    const float* g_bl[4]  = {(const float*)d_in[8],  (const float*)d_in[14], (const float*)d_in[20], (const float*)d_in[26]};
    const float* g_wr[4]  = {(const float*)d_in[9],  (const float*)d_in[15], (const float*)d_in[21], (const float*)d_in[27]};
    const float* g_br[4]  = {(const float*)d_in[10], (const float*)d_in[16], (const float*)d_in[22], (const float*)d_in[28]};
    const float* g_att[4] = {(const float*)d_in[11], (const float*)d_in[17], (const float*)d_in[23], (const float*)d_in[29]};
    const float* g_b[4]   = {(const float*)d_in[12], (const float*)d_in[18], (const float*)d_in[24], (const float*)d_in[30]};
    const float* lab_w = (const float*)d_in[31];
    const float* lab_b = (const float*)d_in[32];
    const float* val_w = (const float*)d_in[33];
    const float* val_b = (const float*)d_in[34];
    const float* skw   = (const float*)d_in[35];
    const float* skb   = (const float*)d_in[36];

    float* out = (float*)d_out;
    float* o0 = out;            // batch[:,:,:4]   32768
    float* o1 = out + 32768;    // batch[:,:,4:5]   8192
    float* o2 = out + 40960;    // logits          32768
    float* o3 = out + 73728;    // values           8192
    float* o4 = out + 81920;    // latent          24576  (doubles as latf)
    float* o5 = out + 106496;   // adj           1048576
    float* o6 = out + 1155072;  // edge_dist     1048576

    // Scratch: 6.25 MB.
    char* p = (char*)d_ws;
    auto carve = [&](size_t bytes) { void* r = (void*)p; p += (bytes + 255) & ~(size_t)255; return r; };
    double*   aos  = (double*)  carve((size_t)BB * NN * 4 * 8);   // 256 KB
    unsigned* hl2p = (unsigned*)carve((size_t)BB * NN * 32 * 4);  // 1 MB
    unsigned* hr2p = (unsigned*)carve((size_t)BB * NN * 32 * 4);
    unsigned* hl3p = (unsigned*)carve((size_t)BB * NN * 32 * 4);
    unsigned* hr3p = (unsigned*)carve((size_t)BB * NN * 32 * 4);
    unsigned* hl4p = (unsigned*)carve((size_t)BB * NN * 32 * 4);
    unsigned* hr4p = (unsigned*)carve((size_t)BB * NN * 32 * 4);

    enc_kernel<<<dim3(BB, 4), 256, 0, stream>>>(batch, enc_w1, enc_b1, enc_w2, enc_b2,
                                                enc_w3, enc_b3, aos, o0, o1, o4, o5);
    gabriel_kernel<<<dim3(32, BB), 256, 0, stream>>>(aos, o5, o6);

    // layer 1 (lin1 + lin2 fused) -> hl2p/hr2p
    attnA_kernel<<<BB * 16, 256, 0, stream>>>(o4,
        g_wl[0], g_bl[0], g_wr[0], g_br[0], g_att[0], g_b[0], o5,
        g_wl[1], g_bl[1], g_wr[1], g_br[1], hl2p, hr2p);
    // layer 2 (lin3 + lin4 fused) -> hl3p/hr3p/hl4p/hr4p
    attnB_kernel<<<BB * 16, 256, 0, stream>>>(hl2p, hr2p,
        g_att[1], g_b[1], o5,
        g_wl[2], g_bl[2], g_wr[2], g_br[2],
        g_wl[3], g_bl[3], g_wr[3], g_br[3],
        hl3p, hr3p, hl4p, hr4p);
    // layers 3 + 4 with skip + heads -> o2/o3
    attnCD_kernel<<<dim3(BB * 16, 2), 256, 0, stream>>>(hl3p, hr3p, hl4p, hr4p,
        g_att[2], g_b[2], g_att[3], g_b[3], o5, o4, skw, skb,
        lab_w, lab_b, o2, val_w, val_b, o3);
}

// Round 14
// 266.091 us; speedup vs baseline: 1.1278x; 1.0037x over previous
//
#include <hip/hip_runtime.h>

#define BB 64
#define NN 128
#define INF_ 5
#define LATD 3
#define HIDD 64

__device__ __forceinline__ float bflo(unsigned u) { return __uint_as_float(u << 16); }
__device__ __forceinline__ float bfhi(unsigned u) { return __uint_as_float(u & 0xffff0000u); }
__device__ __forceinline__ unsigned bfpack(float a, float b) {
    unsigned ua = __float_as_uint(a), ub = __float_as_uint(b);
    unsigned ra = (ua + 0x7fffu + ((ua >> 16) & 1u)) >> 16;   // RNE
    unsigned rb = (ub + 0x7fffu + ((ub >> 16) & 1u)) >> 16;
    return ra | (rb << 16);
}

// ---------------------------------------------------------------------------
// Encoder (f64, expressions unchanged since r5 -> adjacency bits stable).
// Also zeroes o5/o6. Grid (B,4).  [frozen since r9]
// ---------------------------------------------------------------------------
__global__ __launch_bounds__(256) void enc_kernel(
    const float* __restrict__ batch,
    const float* __restrict__ w1, const float* __restrict__ b1,
    const float* __restrict__ w2, const float* __restrict__ b2,
    const float* __restrict__ w3, const float* __restrict__ b3,
    double* __restrict__ aos,
    float* __restrict__ o0, float* __restrict__ o1, float* __restrict__ o4,
    float* __restrict__ o5)
{
    const int b = blockIdx.x;
    const int n0 = blockIdx.y * 32;
    const int tid = threadIdx.x;
    const int w = tid >> 6, lane = tid & 63;

    {   // zero adj + edge_dist (contiguous 8 MB starting at o5)
        const int blk = blockIdx.x * 4 + blockIdx.y;      // 0..255
        float4* z = (float4*)o5 + (size_t)blk * 2048;
        float4 zero = make_float4(0.f, 0.f, 0.f, 0.f);
        for (int q = tid; q < 2048; q += 256) z[q] = zero;
    }

    __shared__ double xs[32][6];
    __shared__ double w1s[INF_][HIDD];
    __shared__ float  w2s[HIDD * HIDD];
    __shared__ double w3s[HIDD][LATD];
    __shared__ double b1s[HIDD], b2s[HIDD], b3s[LATD];

    for (int idx = tid; idx < 32 * INF_; idx += 256) {
        int n = idx / INF_, c = idx % INF_;
        float v = batch[((size_t)b * NN + n0 + n) * INF_ + c];
        xs[n][c] = (double)v;
        if (c < 4) o0[((size_t)b * NN + n0 + n) * 4 + c] = v;
        else       o1[(size_t)b * NN + n0 + n] = v;
    }
    for (int idx = tid; idx < INF_ * HIDD; idx += 256)
        w1s[idx / HIDD][idx % HIDD] = (double)w1[idx];
    for (int idx = tid; idx < HIDD * HIDD; idx += 256)
        w2s[idx] = w2[idx];
    for (int idx = tid; idx < HIDD * LATD; idx += 256)
        w3s[idx / LATD][idx % LATD] = (double)w3[idx];
    if (tid < HIDD) {
        b1s[tid] = (double)b1[tid];
        b2s[tid] = (double)b2[tid];
    }
    if (tid < LATD) b3s[tid] = (double)b3[tid];
    __syncthreads();

    for (int r = 0; r < 8; ++r) {
        const int nl = w * 8 + r;
        const int n = n0 + nl;
        double h1v = b1s[lane];
        for (int k = 0; k < INF_; ++k) h1v += xs[nl][k] * w1s[k][lane];
        h1v = fmax(h1v, 0.0);
        double h2v = b2s[lane];
        for (int k = 0; k < HIDD; ++k) {
            double h1k = __shfl(h1v, k, 64);
            h2v += h1k * (double)w2s[k * HIDD + lane];
        }
        h2v = fmax(h2v, 0.0);
        double l0 = h2v * w3s[lane][0];
        double l1 = h2v * w3s[lane][1];
        double l2 = h2v * w3s[lane][2];
        for (int o = 32; o >= 1; o >>= 1) {
            l0 += __shfl_xor(l0, o, 64);
            l1 += __shfl_xor(l1, o, 64);
            l2 += __shfl_xor(l2, o, 64);
        }
        l0 += b3s[0]; l1 += b3s[1]; l2 += b3s[2];
        if (lane == 0) {
            double* A = aos + ((size_t)b * NN + n) * 4;
            A[0] = l0; A[1] = l1; A[2] = l2;
            A[3] = l0 * l0 + l1 * l1 + l2 * l2;
        }
        if (lane < LATD) {
            double lv = (lane == 0) ? l0 : ((lane == 1) ? l1 : l2);
            o4[((size_t)b * NN + n) * LATD + lane] = (float)lv;
        }
    }
}

// ---------------------------------------------------------------------------
// Gabriel (frozen since r9): wave = pair stream with j-parity split,
// lane = witness k in registers, identity d2-r2 == (pk-pi).(pk-pj).
// ---------------------------------------------------------------------------
__global__ __launch_bounds__(256) void gabriel_kernel(
    const double* __restrict__ aos,
    float* __restrict__ o5, float* __restrict__ o6)
{
    const int b = blockIdx.y;
    const int w = threadIdx.x >> 6, lane = threadIdx.x & 63;
    const int u = blockIdx.x * 4 + w;          // 0..127
    const int v = u >> 1, par = u & 1;

    __shared__ double4 Ps[NN];
    const double2* src = (const double2*)(aos + (size_t)b * NN * 4);
    double2* dst = (double2*)Ps;
    for (int idx = threadIdx.x; idx < NN * 2; idx += 256) dst[idx] = src[idx];
    __syncthreads();

    const double4 A  = Ps[lane];
    const double4 Bq = Ps[lane + 64];

    for (int half = 0; half < 2; ++half) {
        const int i = (half == 0) ? v : 126 - v;
        if (half == 1 && i == v) break;
        const int jstart = (half == 0) ? (v + 1) : (127 - v);
        const int j0 = jstart + ((jstart ^ par) & 1);
        const double4 pi = Ps[i];
        const double aix = A.x - pi.x,  aiy = A.y - pi.y,  aiz = A.z - pi.z;
        const double bix = Bq.x - pi.x, biy = Bq.y - pi.y, biz = Bq.z - pi.z;
        const bool mA = (lane != i), mB = (lane + 64 != i);
        for (int j = j0; j < NN; j += 2) {
            double4 pj = Ps[j];
            double ajx = A.x - pj.x,  ajy = A.y - pj.y,  ajz = A.z - pj.z;
            double bjx = Bq.x - pj.x, bjy = Bq.y - pj.y, bjz = Bq.z - pj.z;
            double dA = aix * ajx + aiy * ajy + aiz * ajz;
            double dB = bix * bjx + biy * bjy + biz * bjz;
            bool tA = (dA < 0.0) && mA && (lane != j);
            bool tB = (dB < 0.0) && mB && (lane + 64 != j);
            if (!__any(tA || tB)) {
                if (lane == 0) {
                    double dx = pi.x - pj.x, dy = pi.y - pj.y, dz = pi.z - pj.z;
                    float d = (float)sqrt(dx * dx + dy * dy + dz * dz);
                    size_t ij = ((size_t)b * NN + i) * NN + j;
                    size_t ji = ((size_t)b * NN + j) * NN + i;
                    o5[ij] = 1.0f; o5[ji] = 1.0f;
                    o6[ij] = d;    o6[ji] = d;
                }
            }
        }
    }
}

// ---------------------------------------------------------------------------
// Attention v7 = r13 v6 + (a) uint4 staging loads (16 -> 4 VMEM instrs per
// thread draining the post-poison-fill HBM-latency reads), (b) attnB stages
// all FOUR epilogue W matrices bf16-packed in ONE 32 KB round (5 -> 3
// barriers; outputs are bf16-packed anyway so W-bf16 error is 2nd-order).
// ---------------------------------------------------------------------------
struct AttnS {
    float  hls[NN * 66];     // 33792 B (reused as packed-W buffer in epilogue)
    float2 as2[4][NN];       //  4096 B (wave-private; reused as x buffer)
    float2 hr2[8][32];       //  2048 B
    float2 att2[32];         //   256 B
};

__device__ __forceinline__ void attn_stage_packed(
    AttnS& s, int tid, int b, int i0,
    const unsigned* __restrict__ hlp, const unsigned* __restrict__ hrp,
    const float* __restrict__ att)
{
    const uint4* src = (const uint4*)(hlp + (size_t)b * NN * 32);  // NN*8 uint4
    for (int idx = tid; idx < NN * 8; idx += 256) {
        int j = idx >> 3, q = idx & 7;
        uint4 u = src[idx];
        float* d = &s.hls[j * 66 + 8 * q];
        *(float2*)&d[0] = make_float2(bflo(u.x), bfhi(u.x));
        *(float2*)&d[2] = make_float2(bflo(u.y), bfhi(u.y));
        *(float2*)&d[4] = make_float2(bflo(u.z), bfhi(u.z));
        *(float2*)&d[6] = make_float2(bflo(u.w), bfhi(u.w));
    }
    unsigned u = hrp[((size_t)b * NN + i0) * 32 + tid];   // 8 rows * 32 words
    ((float2*)s.hr2)[tid] = make_float2(bflo(u), bfhi(u));
    if (tid < 32) s.att2[tid] = make_float2(att[2 * tid], att[2 * tid + 1]);
}

// Phase A (scores+softmax) + Phase B (aggregation). Caller barriers staging.
__device__ __forceinline__ void attn_phase(
    AttnS& s, int b, int i0, int w, int lane,
    const float* __restrict__ adjf, float& agg0, float& agg1)
{
    const int il0 = w * 2, il1 = il0 + 1;
    const int i_0 = i0 + il0, i_1 = i0 + il1;

    // hoist adjacency loads (global, ~500 cyc) above the score loop
    const float* ar0 = adjf + ((size_t)b * NN + i_0) * NN;
    const float* ar1 = adjf + ((size_t)b * NN + i_1) * NN;
    float ad00 = ar0[lane], ad01 = ar0[lane + 64];
    float ad10 = ar1[lane], ad11 = ar1[lane + 64];

    float s00 = 0.f, s01 = 0.f, s10 = 0.f, s11 = 0.f;
    {
        const float* hl0 = &s.hls[lane * 66];
        const float* hl1 = &s.hls[(lane + 64) * 66];
        #pragma unroll
        for (int c = 0; c < 32; ++c) {
            float2 av = s.att2[c];
            float2 r0 = s.hr2[il0][c];
            float2 r1 = s.hr2[il1][c];
            float2 g0 = *(const float2*)&hl0[2 * c];
            float2 g1 = *(const float2*)&hl1[2 * c];
            float e;
            e = r0.x + g0.x; e = fmaxf(e, 0.2f * e); s00 = fmaf(av.x, e, s00);
            e = r0.y + g0.y; e = fmaxf(e, 0.2f * e); s00 = fmaf(av.y, e, s00);
            e = r0.x + g1.x; e = fmaxf(e, 0.2f * e); s01 = fmaf(av.x, e, s01);
            e = r0.y + g1.y; e = fmaxf(e, 0.2f * e); s01 = fmaf(av.y, e, s01);
            e = r1.x + g0.x; e = fmaxf(e, 0.2f * e); s10 = fmaf(av.x, e, s10);
            e = r1.y + g0.y; e = fmaxf(e, 0.2f * e); s10 = fmaf(av.y, e, s10);
            e = r1.x + g1.x; e = fmaxf(e, 0.2f * e); s11 = fmaf(av.x, e, s11);
            e = r1.y + g1.y; e = fmaxf(e, 0.2f * e); s11 = fmaf(av.y, e, s11);
        }
    }
    if (!((ad00 != 0.f) || (lane == i_0)))      s00 = -1e30f;
    if (!((ad01 != 0.f) || (lane + 64 == i_0))) s01 = -1e30f;
    if (!((ad10 != 0.f) || (lane == i_1)))      s10 = -1e30f;
    if (!((ad11 != 0.f) || (lane + 64 == i_1))) s11 = -1e30f;

    float m0 = fmaxf(s00, s01), m1 = fmaxf(s10, s11);
    for (int o = 32; o >= 1; o >>= 1) {
        m0 = fmaxf(m0, __shfl_xor(m0, o, 64));
        m1 = fmaxf(m1, __shfl_xor(m1, o, 64));
    }
    float e00 = __expf(s00 - m0), e01 = __expf(s01 - m0);
    float e10 = __expf(s10 - m1), e11 = __expf(s11 - m1);
    float z0 = e00 + e01, z1 = e10 + e11;
    for (int o = 32; o >= 1; o >>= 1) {
        z0 += __shfl_xor(z0, o, 64);
        z1 += __shfl_xor(z1, o, 64);
    }
    float iv0 = 1.f / z0, iv1 = 1.f / z1;
    s.as2[w][lane]      = make_float2(e00 * iv0, e10 * iv1);
    s.as2[w][lane + 64] = make_float2(e01 * iv0, e11 * iv1);
    float o0a = 0.f, o1a = 0.f;
    for (int j = 0; j < NN; ++j) {
        float2 av = s.as2[w][j];
        float hv = s.hls[j * 66 + lane];
        o0a = fmaf(av.x, hv, o0a);
        o1a = fmaf(av.y, hv, o1a);
    }
    agg0 = o0a; agg1 = o1a;
}

// Stage two 16 KB f32 weight matrices into the dead hls region (attnA).
__device__ __forceinline__ void stage_w2(
    AttnS& s, int tid, const float* __restrict__ wa, const float* __restrict__ wb)
{
    float4* d4 = (float4*)s.hls;
    const float4* a4 = (const float4*)wa;
    const float4* b4 = (const float4*)wb;
    for (int idx = tid; idx < 1024; idx += 256) d4[idx] = a4[idx];
    for (int idx = tid; idx < 1024; idx += 256) d4[1024 + idx] = b4[idx];
}

// Stage FOUR weight matrices bf16-packed (4 x 8 KB = 32 KB) in one round.
__device__ __forceinline__ void stage_w4_bf16(
    AttnS& s, int tid,
    const float* __restrict__ wa, const float* __restrict__ wb,
    const float* __restrict__ wc, const float* __restrict__ wd)
{
    unsigned* dst = (unsigned*)s.hls;
    const float4* srcs[4] = {(const float4*)wa, (const float4*)wb,
                             (const float4*)wc, (const float4*)wd};
    #pragma unroll
    for (int m = 0; m < 4; ++m) {
        const float4* sm = srcs[m];
        for (int idx = tid; idx < 1024; idx += 256) {
            float4 v = sm[idx];
            dst[m * 2048 + 2 * idx]     = bfpack(v.x, v.y);
            dst[m * 2048 + 2 * idx + 1] = bfpack(v.z, v.w);
        }
    }
}

// Matvec, f32 W in LDS (attnA): x from wave-private as2 row (b64 broadcast),
// W lane-indexed (2-way alias, free). No barriers inside.
__device__ __forceinline__ void mv_lds(
    AttnS& s, const float* __restrict__ Wlds, int w, int lane, int b, int i0,
    const float* __restrict__ bvec, unsigned* __restrict__ outp)
{
    float acc0 = bvec[lane], acc1 = acc0;
    #pragma unroll
    for (int h = 0; h < HIDD; ++h) {
        float2 xv = s.as2[w][h];
        float wv = Wlds[h * HIDD + lane];
        acc0 = fmaf(xv.x, wv, acc0);
        acc1 = fmaf(xv.y, wv, acc1);
    }
    float p0 = __shfl_xor(acc0, 1, 64);
    float p1 = __shfl_xor(acc1, 1, 64);
    if ((lane & 1) == 0) {
        outp[((size_t)b * NN + i0 + w * 2 + 0) * 32 + (lane >> 1)] = bfpack(acc0, p0);
        outp[((size_t)b * NN + i0 + w * 2 + 1) * 32 + (lane >> 1)] = bfpack(acc1, p1);
    }
}

// Matvec, bf16-packed W in LDS (attnB): lane pairs read the same word
// (same-address broadcast, free), halfword selected per lane.
__device__ __forceinline__ void mv_ldsbf(
    AttnS& s, const unsigned* __restrict__ Wp, int w, int lane, int b, int i0,
    const float* __restrict__ bvec, unsigned* __restrict__ outp)
{
    float acc0 = bvec[lane], acc1 = acc0;
    const bool hi = (lane & 1);
    const int wid = lane >> 1;
    #pragma unroll
    for (int h = 0; h < HIDD; ++h) {
        float2 xv = s.as2[w][h];
        unsigned uw = Wp[h * 32 + wid];
        float wv = hi ? bfhi(uw) : bflo(uw);
        acc0 = fmaf(xv.x, wv, acc0);
        acc1 = fmaf(xv.y, wv, acc1);
    }
    float p0 = __shfl_xor(acc0, 1, 64);
    float p1 = __shfl_xor(acc1, 1, 64);
    if ((lane & 1) == 0) {
        outp[((size_t)b * NN + i0 + w * 2 + 0) * 32 + (lane >> 1)] = bfpack(acc0, p0);
        outp[((size_t)b * NN + i0 + w * 2 + 1) * 32 + (lane >> 1)] = bfpack(acc1, p1);
    }
}

// ---- layer 1: lin1 folded into staging (Cin=1), lin2 folded into epilogue --
__global__ __launch_bounds__(256, 4) void attnA_kernel(
    const float* __restrict__ latf,
    const float* __restrict__ wl1, const float* __restrict__ bl1,
    const float* __restrict__ wr1, const float* __restrict__ br1,
    const float* __restrict__ att, const float* __restrict__ bias,
    const float* __restrict__ adjf,
    const float* __restrict__ wl2, const float* __restrict__ bl2,
    const float* __restrict__ wr2, const float* __restrict__ br2,
    unsigned* __restrict__ hl2p, unsigned* __restrict__ hr2p)
{
    __shared__ AttnS s;
    const int bx = blockIdx.x;
    const int b = bx >> 4, i0 = (bx & 15) << 3;
    const int tid = threadIdx.x, w = tid >> 6, lane = tid & 63;

    {   // hl1[j][h] = x0[j]*wl1[h] + bl1[h];  x0 = latent[...,2] (wave-uniform)
        float wv = wl1[lane], bv = bl1[lane];
        for (int m = 0; m < 32; ++m) {
            int j = w + 4 * m;
            float x0 = latf[((size_t)b * NN + j) * LATD + 2];
            s.hls[j * 66 + lane] = fmaf(x0, wv, bv);
        }
    }
    {   // hr1 for this block's 8 rows
        int il = tid >> 5, c = tid & 31;
        float x0 = latf[((size_t)b * NN + i0 + il) * LATD + 2];
        s.hr2[il][c] = make_float2(fmaf(x0, wr1[2 * c], br1[2 * c]),
                                   fmaf(x0, wr1[2 * c + 1], br1[2 * c + 1]));
    }
    if (tid < 32) s.att2[tid] = make_float2(att[2 * tid], att[2 * tid + 1]);
    float bsv = bias[lane];
    __syncthreads();

    float agg0, agg1;
    attn_phase(s, b, i0, w, lane, adjf, agg0, agg1);
    float out0 = fmaxf(agg0 + bsv, 0.f);
    float out1 = fmaxf(agg1 + bsv, 0.f);
    s.as2[w][lane] = make_float2(out0, out1);     // wave-private x buffer
    __syncthreads();                               // all waves done with hls
    stage_w2(s, tid, wl2, wr2);
    __syncthreads();
    mv_lds(s, s.hls,        w, lane, b, i0, bl2, hl2p);
    mv_lds(s, s.hls + 4096, w, lane, b, i0, br2, hr2p);
}

// ---- layer 2: lin3 + lin4 folded into epilogue (ONE bf16 W round) ---------
__global__ __launch_bounds__(256, 4) void attnB_kernel(
    const unsigned* __restrict__ hlp, const unsigned* __restrict__ hrp,
    const float* __restrict__ att, const float* __restrict__ bias,
    const float* __restrict__ adjf,
    const float* __restrict__ wl3, const float* __restrict__ bl3,
    const float* __restrict__ wr3, const float* __restrict__ br3,
    const float* __restrict__ wl4, const float* __restrict__ bl4,
    const float* __restrict__ wr4, const float* __restrict__ br4,
    unsigned* __restrict__ hl3p, unsigned* __restrict__ hr3p,
    unsigned* __restrict__ hl4p, unsigned* __restrict__ hr4p)
{
    __shared__ AttnS s;
    const int bx = blockIdx.x;
    const int b = bx >> 4, i0 = (bx & 15) << 3;
    const int tid = threadIdx.x, w = tid >> 6, lane = tid & 63;

    attn_stage_packed(s, tid, b, i0, hlp, hrp, att);
    float bsv = bias[lane];
    __syncthreads();

    float agg0, agg1;
    attn_phase(s, b, i0, w, lane, adjf, agg0, agg1);
    float out0 = fmaxf(agg0 + bsv, 0.f);
    float out1 = fmaxf(agg1 + bsv, 0.f);
    s.as2[w][lane] = make_float2(out0, out1);     // wave-private x buffer
    __syncthreads();                               // all waves done with hls
    stage_w4_bf16(s, tid, wl3, wr3, wl4, wr4);
    __syncthreads();
    const unsigned* Wp = (const unsigned*)s.hls;
    mv_ldsbf(s, Wp,        w, lane, b, i0, bl3, hl3p);
    mv_ldsbf(s, Wp + 2048, w, lane, b, i0, br3, hr3p);
    mv_ldsbf(s, Wp + 4096, w, lane, b, i0, bl4, hl4p);
    mv_ldsbf(s, Wp + 6144, w, lane, b, i0, br4, hr4p);
}

// ---- layers 3 & 4: skip + output heads ------------------------------------
template <int C>
__device__ __forceinline__ void attn_head(
    AttnS& s, int tid, int b, int i0,
    const unsigned* __restrict__ hlp, const unsigned* __restrict__ hrp,
    const float* __restrict__ att, const float* __restrict__ bias,
    const float* __restrict__ adjf, const float* __restrict__ latf,
    const float* __restrict__ skw, const float* __restrict__ skb,
    const float* __restrict__ head_w, const float* __restrict__ head_b,
    float* __restrict__ head_out)
{
    const int w = tid >> 6, lane = tid & 63;
    attn_stage_packed(s, tid, b, i0, hlp, hrp, att);
    float bsv = bias[lane];
    float sw0 = skw[lane], sw1 = skw[64 + lane], sw2 = skw[128 + lane];
    float sbv = skb[lane];
    __syncthreads();

    float agg0, agg1;
    attn_phase(s, b, i0, w, lane, adjf, agg0, agg1);

    #pragma unroll
    for (int r = 0; r < 2; ++r) {
        const int i = i0 + w * 2 + r;
        float out = ((r == 0) ? agg0 : agg1) + bsv;
        const float* lr = latf + ((size_t)b * NN + i) * LATD;
        float sk = sbv;
        sk = fmaf(lr[0], sw0, sk);
        sk = fmaf(lr[1], sw1, sk);
        sk = fmaf(lr[2], sw2, sk);
        out = fmaxf(out + 0.1f * sk, 0.f);
        float hv[C];
        #pragma unroll
        for (int c = 0; c < C; ++c) {
            float vv = out * head_w[lane * C + c];
            for (int o = 32; o >= 1; o >>= 1) vv += __shfl_xor(vv, o, 64);
            hv[c] = vv + head_b[c];
        }
        if (lane == 0)
            for (int c = 0; c < C; ++c)
                head_out[((size_t)b * NN + i) * C + c] = hv[c];
    }
}

__global__ __launch_bounds__(256, 4) void attnCD_kernel(
    const unsigned* __restrict__ hl3p, const unsigned* __restrict__ hr3p,
    const unsigned* __restrict__ hl4p, const unsigned* __restrict__ hr4p,
    const float* __restrict__ att3, const float* __restrict__ b3,
    const float* __restrict__ att4, const float* __restrict__ b4,
    const float* __restrict__ adjf, const float* __restrict__ latf,
    const float* __restrict__ skw, const float* __restrict__ skb,
    const float* __restrict__ lab_w, const float* __restrict__ lab_b, float* __restrict__ o2,
    const float* __restrict__ val_w, const float* __restrict__ val_b, float* __restrict__ o3)
{
    __shared__ AttnS s;
    const int b = blockIdx.x >> 4, i0 = (blockIdx.x & 15) << 3;
    if (blockIdx.y == 0)
        attn_head<4>(s, threadIdx.x, b, i0, hl3p, hr3p, att3, b3, adjf, latf,
                     skw, skb, lab_w, lab_b, o2);
    else
        attn_head<1>(s, threadIdx.x, b, i0, hl4p, hr4p, att4, b4, adjf, latf,
                     skw, skb, val_w, val_b, o3);
}

// ---------------------------------------------------------------------------
extern "C" void kernel_launch(void* const* d_in, const int* in_sizes, int n_in,
                              void* d_out, int out_size, void* d_ws, size_t ws_size,
                              hipStream_t stream)
{
    const float* batch  = (const float*)d_in[0];
    const float* enc_w1 = (const float*)d_in[1];
    const float* enc_b1 = (const float*)d_in[2];
    const float* enc_w2 = (const float*)d_in[3];
    const float* enc_b2 = (const float*)d_in[4];
    const float* enc_w3 = (const float*)d_in[5];
    const float* enc_b3 = (const float*)d_in[6];
    const float* g_wl[4]  = {(const float*)d_in[7],  (const float*)d_in[13], (const float*)d_in[19], (const float*)d_in[25]};
    const float* g_bl[4]  = {(const float*)d_in[8],  (const float*)d_in[14], (const float*)d_in[20], (const float*)d_in[26]};
    const float* g_wr[4]  = {(const float*)d_in[9],  (const float*)d_in[15], (const float*)d_in[21], (const float*)d_in[27]};
    const float* g_br[4]  = {(const float*)d_in[10], (const float*)d_in[16], (const float*)d_in[22], (const float*)d_in[28]};
    const float* g_att[4] = {(const float*)d_in[11], (const float*)d_in[17], (const float*)d_in[23], (const float*)d_in[29]};
    const float* g_b[4]   = {(const float*)d_in[12], (const float*)d_in[18], (const float*)d_in[24], (const float*)d_in[30]};
    const float* lab_w = (const float*)d_in[31];
    const float* lab_b = (const float*)d_in[32];
    const float* val_w = (const float*)d_in[33];
    const float* val_b = (const float*)d_in[34];
    const float* skw   = (const float*)d_in[35];
    const float* skb   = (const float*)d_in[36];

    float* out = (float*)d_out;
    float* o0 = out;            // batch[:,:,:4]   32768
    float* o1 = out + 32768;    // batch[:,:,4:5]   8192
    float* o2 = out + 40960;    // logits          32768
    float* o3 = out + 73728;    // values           8192
    float* o4 = out + 81920;    // latent          24576  (doubles as latf)
    float* o5 = out + 106496;   // adj           1048576
    float* o6 = out + 1155072;  // edge_dist     1048576

    // Scratch: 6.25 MB.
    char* p = (char*)d_ws;
    auto carve = [&](size_t bytes) { void* r = (void*)p; p += (bytes + 255) & ~(size_t)255; return r; };
    double*   aos  = (double*)  carve((size_t)BB * NN * 4 * 8);   // 256 KB
    unsigned* hl2p = (unsigned*)carve((size_t)BB * NN * 32 * 4);  // 1 MB
    unsigned* hr2p = (unsigned*)carve((size_t)BB * NN * 32 * 4);
    unsigned* hl3p = (unsigned*)carve((size_t)BB * NN * 32 * 4);
    unsigned* hr3p = (unsigned*)carve((size_t)BB * NN * 32 * 4);
    unsigned* hl4p = (unsigned*)carve((size_t)BB * NN * 32 * 4);
    unsigned* hr4p = (unsigned*)carve((size_t)BB * NN * 32 * 4);

    enc_kernel<<<dim3(BB, 4), 256, 0, stream>>>(batch, enc_w1, enc_b1, enc_w2, enc_b2,
                                                enc_w3, enc_b3, aos, o0, o1, o4, o5);
    gabriel_kernel<<<dim3(32, BB), 256, 0, stream>>>(aos, o5, o6);

    // layer 1 (lin1 + lin2 fused) -> hl2p/hr2p
    attnA_kernel<<<BB * 16, 256, 0, stream>>>(o4,
        g_wl[0], g_bl[0], g_wr[0], g_br[0], g_att[0], g_b[0], o5,
        g_wl[1], g_bl[1], g_wr[1], g_br[1], hl2p, hr2p);
    // layer 2 (lin3 + lin4 fused) -> hl3p/hr3p/hl4p/hr4p
    attnB_kernel<<<BB * 16, 256, 0, stream>>>(hl2p, hr2p,
        g_att[1], g_b[1], o5,
        g_wl[2], g_bl[2], g_wr[2], g_br[2],
        g_wl[3], g_bl[3], g_wr[3], g_br[3],
        hl3p, hr3p, hl4p, hr4p);
    // layers 3 + 4 with skip + heads -> o2/o3
    attnCD_kernel<<<dim3(BB * 16, 2), 256, 0, stream>>>(hl3p, hr3p, hl4p, hr4p,
        g_att[2], g_b[2], g_att[3], g_b[3], o5, o4, skw, skb,
        lab_w, lab_b, o2, val_w, val_b, o3);
}